// Round 3
// baseline (2487.280 us; speedup 1.0000x reference)
//
#include <hip/hip_runtime.h>
#include <math.h>

#define B_ 128
#define T_ 200
#define D_ 784
#define H_ 500
#define O_ 10
#define N_ROWS 25600          // B_*T_
#define BD 100352             // B_*D_
#define BH 64000              // B_*H_
#define DECAY_M 0.77880078307140487f

// workspace layout (bytes)
#define OFF_BUFC   80281600ULL                 // 25600*784*4
#define OFF_BUFE   131481600ULL                // + 25600*500*4
#define OFF_STATS  132505600ULL                // + 25600*10*4
#define OFF_SAVE1  132518144ULL                // + 1568*8
#define OFF_SAVE2  132518944ULL                // + 200*4
#define WS_REQUIRED 132519744ULL               // + 200*4

// ---------------------------------------------------------------------------
// Generic GEMM, fp64 accumulation: C[N,M] = A[N,K] * W[M,K]^T + bias[M]
// 128x128 tile, BK=16, 256 threads, 8x8 microtile. LDS stride 132 (fp32).
// ---------------------------------------------------------------------------
__global__ __launch_bounds__(256) void gemm_bias(
    const float* __restrict__ A, const float* __restrict__ W,
    const float* __restrict__ bias, float* __restrict__ C,
    int N, int K, int M) {
  __shared__ float As[16][132];
  __shared__ float Bs[16][132];
  const int tid = threadIdx.x;
  const int tx = tid & 15, ty = tid >> 4;
  const int m0 = blockIdx.x * 128;
  const int n0 = blockIdx.y * 128;

  double acc[8][8];
#pragma unroll
  for (int i = 0; i < 8; ++i)
#pragma unroll
    for (int j = 0; j < 8; ++j) acc[i][j] = 0.0;

  const int Kt = (K + 15) >> 4;
  for (int kt = 0; kt < Kt; ++kt) {
    const int k0 = kt << 4;
#pragma unroll
    for (int it = 0; it < 2; ++it) {
      int idx = tid + it * 256;
      int row = idx >> 2;
      int c4 = (idx & 3) << 2;
      int gr = n0 + row, gc = k0 + c4;
      float4 v = make_float4(0.f, 0.f, 0.f, 0.f);
      if (gr < N && gc + 3 < K) v = *(const float4*)(A + (size_t)gr * K + gc);
      As[c4 + 0][row] = v.x; As[c4 + 1][row] = v.y;
      As[c4 + 2][row] = v.z; As[c4 + 3][row] = v.w;
    }
#pragma unroll
    for (int it = 0; it < 2; ++it) {
      int idx = tid + it * 256;
      int row = idx >> 2;
      int c4 = (idx & 3) << 2;
      int gm = m0 + row, gc = k0 + c4;
      float4 v = make_float4(0.f, 0.f, 0.f, 0.f);
      if (gm < M && gc + 3 < K) v = *(const float4*)(W + (size_t)gm * K + gc);
      Bs[c4 + 0][row] = v.x; Bs[c4 + 1][row] = v.y;
      Bs[c4 + 2][row] = v.z; Bs[c4 + 3][row] = v.w;
    }
    __syncthreads();
#pragma unroll
    for (int k = 0; k < 16; ++k) {
      float a[8], b[8];
      *(float4*)&a[0] = *(const float4*)&As[k][ty * 4];
      *(float4*)&a[4] = *(const float4*)&As[k][64 + ty * 4];
      *(float4*)&b[0] = *(const float4*)&Bs[k][tx * 4];
      *(float4*)&b[4] = *(const float4*)&Bs[k][tx * 4 + 64];
#pragma unroll
      for (int i = 0; i < 8; ++i)
#pragma unroll
        for (int j = 0; j < 8; ++j)
          acc[i][j] = fma((double)a[i], (double)b[j], acc[i][j]);
    }
    __syncthreads();
  }
#pragma unroll
  for (int i = 0; i < 8; ++i) {
    int r = n0 + ((i < 4) ? (ty * 4 + i) : (64 + ty * 4 + i - 4));
    if (r >= N) continue;
#pragma unroll
    for (int j = 0; j < 8; ++j) {
      int c = m0 + ((j < 4) ? (tx * 4 + j) : (64 + tx * 4 + j - 4));
      if (c < M) C[(size_t)r * M + c] = (float)(acc[i][j] + (double)bias[c]);
    }
  }
}

// ---------------------------------------------------------------------------
// GEMM1: reads raw inputs [B, D, T]; output [T][B][D]. fp64 accumulation.
// ---------------------------------------------------------------------------
__global__ __launch_bounds__(256) void gemm1_in(
    const float* __restrict__ X, const float* __restrict__ W,
    const float* __restrict__ bias, float* __restrict__ C) {
  __shared__ float As[16][132];
  __shared__ float Bs[16][132];
  const int tid = threadIdx.x;
  const int tx = tid & 15, ty = tid >> 4;
  const int m0 = blockIdx.x * 128;
  const int n0 = blockIdx.y * 128;

  const int arow = tid & 127;
  const int khalf = tid >> 7;
  const int gr = n0 + arow;
  const int bb = gr / T_;
  const int tt = gr - bb * T_;
  const float* Abase = X + (size_t)bb * (D_ * T_) + tt;

  double acc[8][8];
#pragma unroll
  for (int i = 0; i < 8; ++i)
#pragma unroll
    for (int j = 0; j < 8; ++j) acc[i][j] = 0.0;

  for (int kt = 0; kt < D_ / 16; ++kt) {
    const int k0 = kt << 4;
#pragma unroll
    for (int kk = 0; kk < 8; ++kk) {
      int k = khalf * 8 + kk;
      As[k][arow] = Abase[(size_t)(k0 + k) * T_];
    }
#pragma unroll
    for (int it = 0; it < 2; ++it) {
      int idx = tid + it * 256;
      int row = idx >> 2;
      int c4 = (idx & 3) << 2;
      int gm = m0 + row, gc = k0 + c4;
      float4 v = make_float4(0.f, 0.f, 0.f, 0.f);
      if (gm < D_) v = *(const float4*)(W + (size_t)gm * D_ + gc);
      Bs[c4 + 0][row] = v.x; Bs[c4 + 1][row] = v.y;
      Bs[c4 + 2][row] = v.z; Bs[c4 + 3][row] = v.w;
    }
    __syncthreads();
#pragma unroll
    for (int k = 0; k < 16; ++k) {
      float a[8], b[8];
      *(float4*)&a[0] = *(const float4*)&As[k][ty * 4];
      *(float4*)&a[4] = *(const float4*)&As[k][64 + ty * 4];
      *(float4*)&b[0] = *(const float4*)&Bs[k][tx * 4];
      *(float4*)&b[4] = *(const float4*)&Bs[k][tx * 4 + 64];
#pragma unroll
      for (int i = 0; i < 8; ++i)
#pragma unroll
        for (int j = 0; j < 8; ++j)
          acc[i][j] = fma((double)a[i], (double)b[j], acc[i][j]);
    }
    __syncthreads();
  }
#pragma unroll
  for (int i = 0; i < 8; ++i) {
    int r = n0 + ((i < 4) ? (ty * 4 + i) : (64 + ty * 4 + i - 4));
    int rb = r / T_;
    int rt = r - rb * T_;
    size_t rowoff = ((size_t)rt * B_ + rb) * D_;
#pragma unroll
    for (int j = 0; j < 8; ++j) {
      int c = m0 + ((j < 4) ? (tx * 4 + j) : (64 + tx * 4 + j - 4));
      if (c < D_) C[rowoff + c] = (float)(acc[i][j] + (double)bias[c]);
    }
  }
}

// ---------------------------------------------------------------------------
__global__ __launch_bounds__(256) void bn_stats(const float* __restrict__ Y,
                                                double* __restrict__ stats) {
  int col = blockIdx.x * 256 + threadIdx.x;
  int r0 = blockIdx.y * 256;
  if (col >= D_) return;
  double s = 0.0, s2 = 0.0;
  for (int rr = 0; rr < 256; ++rr) {
    float v = Y[(size_t)(r0 + rr) * D_ + col];
    s += v;
    s2 += (double)v * v;
  }
  atomicAdd(&stats[col], s);
  atomicAdd(&stats[D_ + col], s2);
}

__global__ __launch_bounds__(256) void bn_axon(
    float* __restrict__ Y, const double* __restrict__ stats,
    const float* __restrict__ gamma, const float* __restrict__ beta,
    const float* __restrict__ a1, const float* __restrict__ a2) {
  int j = blockIdx.x * 256 + threadIdx.x;
  int d = j % D_;
  double mean = stats[d] * (1.0 / N_ROWS);
  double var = stats[D_ + d] * (1.0 / N_ROWS) - mean * mean;
  float rstd = (float)(1.0 / sqrt(var + 1e-5));
  float mf = (float)mean;
  float g = gamma[d], be = beta[d];
  float c1 = a1[d], c2 = a2[d];
  float p1 = 0.f, p2 = 0.f;
  for (int t = 0; t < T_; ++t) {
    float x = Y[(size_t)t * BD + j];
    x = g * (x - mf) * rstd + be;
    x = 1.f / (1.f + expf(-x));
    float psp = c1 * p1 + c2 * p2 + x;
    Y[(size_t)t * BD + j] = psp;
    p2 = p1;
    p1 = psp;
  }
}

__global__ __launch_bounds__(256) void lif_axon(
    float* __restrict__ Z, const float* __restrict__ mask,
    const float* __restrict__ a1, const float* __restrict__ a2) {
  int j = blockIdx.x * 256 + threadIdx.x;
  int o = j % H_;
  float c1 = a1[o], c2 = a2[o];
  const float* mrow = mask + (size_t)j * T_;
  float v = 0.f, s = 0.f, p1 = 0.f, p2 = 0.f;
  for (int t = 0; t < T_; ++t) {
    float z = Z[(size_t)t * BH + j];
    v = DECAY_M * v * (1.f - s) + z;
    s = (v > 1.f) ? 1.f : 0.f;
    float sm = s * mrow[t];
    float psp = c1 * p1 + c2 * p2 + sm;
    Z[(size_t)t * BH + j] = psp;
    p2 = p1;
    p1 = psp;
  }
}

__global__ __launch_bounds__(256) void lif_out(const float* __restrict__ Z,
                                               float* __restrict__ out) {
  int j = blockIdx.x * 256 + threadIdx.x;
  if (j >= B_ * O_) return;
  float v = 0.f, s = 0.f;
  for (int t = 0; t < T_; ++t) {
    float z = Z[(size_t)t * (B_ * O_) + j];
    v = DECAY_M * v * (1.f - s) + z;
    s = (v > 1.f) ? 1.f : 0.f;
    out[(size_t)j * T_ + t] = s;
  }
}

// ======================== diagnostic probes =================================
// Each writes a distinct sentinel to a distinct out[] slot ONLY on divergence.
// Earliest-stage sentinels have the largest magnitude (absmax reveals max).

__global__ void probe_ws(unsigned long long ws, float* out) {
  if (ws < WS_REQUIRED) out[0] = 9.0e6f;
}

// GEMM0 check: y1[t=37,b=11,d=123] vs naive ascending fp32 dot
__global__ void probe_g0(const float* X, const float* W, const float* bias,
                         const float* Y, float* out) {
  float acc = 0.f;
  for (int k = 0; k < D_; ++k)
    acc = fmaf(X[11 * (D_ * T_) + k * T_ + 37], W[123 * D_ + k], acc);
  acc += bias[123];
  float got = Y[(size_t)(37 * B_ + 11) * D_ + 123];
  if (!(fabsf(got - acc) < 1e-2f)) out[1] = 8.0e6f;
}

// BN-stats check: recompute channel 205 sums with 256-thread tree reduction
__global__ __launch_bounds__(256) void probe_stats(const float* Y,
                                                   const double* stats,
                                                   float* out) {
  __shared__ double red[256][2];
  int tid = threadIdx.x;
  double s = 0.0, s2 = 0.0;
  for (int r = tid; r < N_ROWS; r += 256) {
    float v = Y[(size_t)r * D_ + 205];
    s += v;
    s2 += (double)v * v;
  }
  red[tid][0] = s; red[tid][1] = s2;
  __syncthreads();
  for (int w = 128; w > 0; w >>= 1) {
    if (tid < w) { red[tid][0] += red[tid + w][0]; red[tid][1] += red[tid + w][1]; }
    __syncthreads();
  }
  if (tid == 0) {
    double ds = fabs(red[0][0] - stats[205]);
    double d2 = fabs(red[0][1] - stats[D_ + 205]);
    if (!(ds < 1e-3 && d2 < 1e-3)) out[2] = 7.0e6f;
  }
}

// save one scan column (stride BD or BH) before in-place overwrite
__global__ void save_col(const float* Y, float* save, int stride, int j0) {
  int t = threadIdx.x;
  if (t < T_) save[t] = Y[(size_t)t * stride + j0];
}

// BN+sigmoid+axon1 replay for (b=3,d=400), verbatim arithmetic
__global__ void probe_bnaxon(const float* save, const float* Y,
                             const double* stats,
                             const float* gamma, const float* beta,
                             const float* a1, const float* a2, float* out) {
  const int d = 400, j0 = 3 * D_ + 400;
  double mean = stats[d] * (1.0 / N_ROWS);
  double var = stats[D_ + d] * (1.0 / N_ROWS) - mean * mean;
  float rstd = (float)(1.0 / sqrt(var + 1e-5));
  float mf = (float)mean;
  float g = gamma[d], be = beta[d];
  float c1 = a1[d], c2 = a2[d];
  float p1 = 0.f, p2 = 0.f, maxd = 0.f;
  for (int t = 0; t < T_; ++t) {
    float x = save[t];
    x = g * (x - mf) * rstd + be;
    x = 1.f / (1.f + expf(-x));
    float psp = c1 * p1 + c2 * p2 + x;
    maxd = fmaxf(maxd, fabsf(psp - Y[(size_t)t * BD + j0]));
    p2 = p1; p1 = psp;
  }
  if (!(maxd < 1e-3f)) out[4] = 6.0e6f;
}

// GEMM1 check: z1[t=91,b=77,o=333] vs naive dot over h1 (bufB, still live)
__global__ void probe_g1(const float* H, const float* W, const float* bias,
                         const float* Z, float* out) {
  const int row = 91 * B_ + 77;
  float acc = 0.f;
  for (int k = 0; k < D_; ++k)
    acc = fmaf(H[(size_t)row * D_ + k], W[333 * D_ + k], acc);
  acc += bias[333];
  float got = Z[(size_t)row * H_ + 333];
  if (!(fabsf(got - acc) < 1e-2f)) out[3] = 5.0e6f;
}

// LIF+mask+axon replay for (b=77,o=333), verbatim arithmetic
__global__ void probe_lif(const float* save, const float* Z,
                          const float* mask, const float* a1, const float* a2,
                          float* out) {
  const int j0 = 77 * H_ + 333, o = 333;
  float c1 = a1[o], c2 = a2[o];
  float v = 0.f, s = 0.f, p1 = 0.f, p2 = 0.f, maxd = 0.f;
  for (int t = 0; t < T_; ++t) {
    float z = save[t];
    v = DECAY_M * v * (1.f - s) + z;
    s = (v > 1.f) ? 1.f : 0.f;
    float sm = s * mask[(size_t)j0 * T_ + t];
    float psp = c1 * p1 + c2 * p2 + sm;
    maxd = fmaxf(maxd, fabsf(psp - Z[(size_t)t * BH + j0]));
    p2 = p1; p1 = psp;
  }
  if (!(maxd < 1e-3f)) out[5] = 4.0e6f;
}

// GEMM2 check: z2[t=123,b=45,o=87] vs naive dot over h2 (bufC live)
__global__ void probe_g2(const float* H, const float* W, const float* bias,
                         const float* Z, float* out) {
  const int row = 123 * B_ + 45;
  float acc = 0.f;
  for (int k = 0; k < H_; ++k)
    acc = fmaf(H[(size_t)row * H_ + k], W[87 * H_ + k], acc);
  acc += bias[87];
  float got = Z[(size_t)row * H_ + 87];
  if (!(fabsf(got - acc) < 1e-2f)) out[6] = 3.0e6f;
}

// GEMM3 check: z3[t=11,b=99,o=7] vs naive dot over h3 (bufB live)
__global__ void probe_g3(const float* H, const float* W, const float* bias,
                         const float* Z, float* out) {
  const int row = 11 * B_ + 99;
  float acc = 0.f;
  for (int k = 0; k < H_; ++k)
    acc = fmaf(H[(size_t)row * H_ + k], W[7 * H_ + k], acc);
  acc += bias[7];
  float got = Z[(size_t)row * O_ + 7];
  if (!(fabsf(got - acc) < 1e-2f)) out[7] = 2.0e6f;
}

// final LIF replay for (b=99,o=7) from z3 (bufE live) vs out
__global__ void probe_lifout(const float* Z, const float* out_r, float* out) {
  const int j0 = 99 * O_ + 7;
  float v = 0.f, s = 0.f, maxd = 0.f;
  for (int t = 0; t < T_; ++t) {
    float z = Z[(size_t)t * (B_ * O_) + j0];
    v = DECAY_M * v * (1.f - s) + z;
    s = (v > 1.f) ? 1.f : 0.f;
    maxd = fmaxf(maxd, fabsf(s - out_r[(size_t)j0 * T_ + t]));
  }
  if (!(maxd < 1e-3f)) out[8] = 1.5e6f;
}

extern "C" void kernel_launch(void* const* d_in, const int* in_sizes, int n_in,
                              void* d_out, int out_size, void* d_ws, size_t ws_size,
                              hipStream_t stream) {
  const float* inputs = (const float*)d_in[0];
  const float* W_mlp  = (const float*)d_in[1];
  const float* b_mlp  = (const float*)d_in[2];
  const float* gamma  = (const float*)d_in[3];
  const float* beta   = (const float*)d_in[4];
  const float* a1_1   = (const float*)d_in[5];
  const float* a2_1   = (const float*)d_in[6];
  const float* W1     = (const float*)d_in[7];
  const float* b1     = (const float*)d_in[8];
  const float* a1_2   = (const float*)d_in[9];
  const float* a2_2   = (const float*)d_in[10];
  const float* W2     = (const float*)d_in[11];
  const float* b2     = (const float*)d_in[12];
  const float* a1_3   = (const float*)d_in[13];
  const float* a2_3   = (const float*)d_in[14];
  const float* W3     = (const float*)d_in[15];
  const float* b3     = (const float*)d_in[16];
  const float* mask1  = (const float*)d_in[17];
  const float* mask2  = (const float*)d_in[18];

  char* ws = (char*)d_ws;
  float* bufB  = (float*)ws;
  float* bufC  = (float*)(ws + OFF_BUFC);
  float* bufE  = (float*)(ws + OFF_BUFE);
  double* stats = (double*)(ws + OFF_STATS);
  float* save1 = (float*)(ws + OFF_SAVE1);
  float* save2 = (float*)(ws + OFF_SAVE2);
  float* out = (float*)d_out;

  // Layer 0
  gemm1_in<<<dim3(7, 200), 256, 0, stream>>>(inputs, W_mlp, b_mlp, bufB);
  probe_g0<<<1, 1, 0, stream>>>(inputs, W_mlp, b_mlp, bufB, out);

  hipMemsetAsync(stats, 0, D_ * 2 * sizeof(double), stream);
  bn_stats<<<dim3(4, 100), 256, 0, stream>>>(bufB, stats);
  probe_stats<<<1, 256, 0, stream>>>(bufB, stats, out);
  save_col<<<1, 256, 0, stream>>>(bufB, save1, BD, 3 * D_ + 400);
  bn_axon<<<BD / 256, 256, 0, stream>>>(bufB, stats, gamma, beta, a1_1, a2_1);
  probe_bnaxon<<<1, 1, 0, stream>>>(save1, bufB, stats, gamma, beta, a1_1, a2_1, out);

  // Layer 1
  gemm_bias<<<dim3(4, 200), 256, 0, stream>>>(bufB, W1, b1, bufC, N_ROWS, D_, H_);
  probe_g1<<<1, 1, 0, stream>>>(bufB, W1, b1, bufC, out);
  save_col<<<1, 256, 0, stream>>>(bufC, save2, BH, 77 * H_ + 333);
  lif_axon<<<BH / 256, 256, 0, stream>>>(bufC, mask1, a1_2, a2_2);
  probe_lif<<<1, 1, 0, stream>>>(save2, bufC, mask1, a1_2, a2_2, out);

  // Layer 2
  gemm_bias<<<dim3(4, 200), 256, 0, stream>>>(bufC, W2, b2, bufB, N_ROWS, H_, H_);
  probe_g2<<<1, 1, 0, stream>>>(bufC, W2, b2, bufB, out);
  lif_axon<<<BH / 256, 256, 0, stream>>>(bufB, mask2, a1_3, a2_3);

  // Layer 3
  gemm_bias<<<dim3(1, 200), 256, 0, stream>>>(bufB, W3, b3, bufE, N_ROWS, H_, O_);
  probe_g3<<<1, 1, 0, stream>>>(bufB, W3, b3, bufE, out);
  lif_out<<<5, 256, 0, stream>>>(bufE, out);
  probe_lifout<<<1, 1, 0, stream>>>(bufE, out, out);

  // workspace-size sentinel (highest priority)
  probe_ws<<<1, 1, 0, stream>>>((unsigned long long)ws_size, out);
}